// Round 1
// baseline (568.217 us; speedup 1.0000x reference)
//
#include <hip/hip_runtime.h>
#include <hip/hip_bf16.h>
#include <stdint.h>

typedef __bf16 bf16x8 __attribute__((ext_vector_type(8)));
typedef float f32x4 __attribute__((ext_vector_type(4)));

static __device__ __forceinline__ unsigned short f2bf(float f) {
  unsigned int u = __float_as_uint(f);
  u += 0x7FFF + ((u >> 16) & 1);   // round-to-nearest-even
  return (unsigned short)(u >> 16);
}

// ---------------- fp32 -> bf16 conversion kernels ----------------

extern "C" __global__ void cvt_bf16_kernel(const float* __restrict__ src,
                                           unsigned short* __restrict__ dst,
                                           long n4) {
  long i = (long)blockIdx.x * blockDim.x + threadIdx.x;
  const long stride = (long)gridDim.x * blockDim.x;
  for (; i < n4; i += stride) {
    const float4 v = ((const float4*)src)[i];
    ushort4 o;
    o.x = f2bf(v.x); o.y = f2bf(v.y); o.z = f2bf(v.z); o.w = f2bf(v.w);
    ((ushort4*)dst)[i] = o;
  }
}

extern "C" __global__ void cvt_pad_kernel(const float* __restrict__ src,
                                          unsigned short* __restrict__ dst,
                                          long nsrc4, long ntot4) {
  long i = (long)blockIdx.x * blockDim.x + threadIdx.x;
  const long stride = (long)gridDim.x * blockDim.x;
  for (; i < ntot4; i += stride) {
    ushort4 o = {0, 0, 0, 0};
    if (i < nsrc4) {
      const float4 v = ((const float4*)src)[i];
      o.x = f2bf(v.x); o.y = f2bf(v.y); o.z = f2bf(v.z); o.w = f2bf(v.w);
    }
    ((ushort4*)dst)[i] = o;
  }
}

// ---------------- bf16 NT GEMM (C = A * Bw^T), 128x128 tile ----------------
// A: M x K row-major bf16.  Bw: N x K row-major bf16 (weights).
// EPI 0: fused first-stage (N=2176): cols [0,1536) -> q_lora bf16 (ws),
//        [1536,2048) -> compressed_kv (out cols 6208..6719),
//        [2048,2112) -> k_pe + RoPE (out cols 6144..6207), [2112,2176) dropped.
// EPI 1: q projection (N=6144): nope cols copied, pe 64-blocks RoPE'd; out cols 0..6143.

template <int EPI>
__global__ __launch_bounds__(256)
void mla_gemm(const __hip_bfloat16* __restrict__ A,
              const __hip_bfloat16* __restrict__ Bw,
              unsigned short* __restrict__ qlora,
              const float* __restrict__ cosp,
              const float* __restrict__ sinp,
              float* __restrict__ out,
              int K) {
  __shared__ __attribute__((aligned(128))) char lds[32768];  // A tile 16KB | B tile 16KB
  const int tid = threadIdx.x;
  const int lane = tid & 63;
  const int wave = tid >> 6;
  const int wr = wave >> 1, wc = wave & 1;
  const long brow = (long)blockIdx.x * 128;
  const int bcol = (int)blockIdx.y * 128;
  const int l15 = lane & 15;
  const int lhi = lane >> 4;

  f32x4 acc[4][4] = {};

  const long a_base = brow * (long)K;
  const long b_base = (long)bcol * (long)K;

  const int nk = K >> 6;
  for (int kt = 0; kt < nk; ++kt) {
    const int k0 = kt << 6;
    __syncthreads();
    // stage 128x64 A-tile and B-tile into LDS (linear [128][64] bf16, 1KB per wave-call)
    #pragma unroll
    for (int i = 0; i < 4; ++i) {
      const int c = wave * 4 + i;               // 16 chunks of 8 rows
      const int r = c * 8 + (lane >> 3);        // tile row
      const int cb = (lane & 7) * 8;            // tile col (bf16)
      const __hip_bfloat16* srcA = A + a_base + (long)r * K + (k0 + cb);
      const __hip_bfloat16* srcB = Bw + b_base + (long)r * K + (k0 + cb);
      __builtin_amdgcn_global_load_lds(
          (__attribute__((address_space(1))) void*)srcA,
          (__attribute__((address_space(3))) void*)(lds + c * 1024), 16, 0, 0);
      __builtin_amdgcn_global_load_lds(
          (__attribute__((address_space(1))) void*)srcB,
          (__attribute__((address_space(3))) void*)(lds + 16384 + c * 1024), 16, 0, 0);
    }
    __syncthreads();
    #pragma unroll
    for (int kk = 0; kk < 2; ++kk) {
      const int koff = kk * 64 + lhi * 16;  // byte offset of 8-elem k-slice
      bf16x8 af[4], bfr[4];
      #pragma unroll
      for (int m = 0; m < 4; ++m)
        af[m] = *(const bf16x8*)(lds + (wr * 64 + m * 16 + l15) * 128 + koff);
      #pragma unroll
      for (int n = 0; n < 4; ++n)
        bfr[n] = *(const bf16x8*)(lds + 16384 + (wc * 64 + n * 16 + l15) * 128 + koff);
      #pragma unroll
      for (int m = 0; m < 4; ++m)
        #pragma unroll
        for (int n = 0; n < 4; ++n)
          acc[m][n] = __builtin_amdgcn_mfma_f32_16x16x32_bf16(af[m], bfr[n], acc[m][n], 0, 0, 0);
    }
  }

  // ---- epilogue ----
  // C/D fragment: col = l15 (within 16-col frag n), row = lhi*4 + r (within 16-row frag m)
  const int wcol = bcol + wc * 64;        // this wave's 64-col block start
  const long r0 = brow + wr * 64 + lhi * 4;

  if constexpr (EPI == 0) {
    if (wcol < 1536) {  // q_lora (bf16, row stride 1536)
      #pragma unroll
      for (int m = 0; m < 4; ++m)
        #pragma unroll
        for (int r = 0; r < 4; ++r) {
          const long row = r0 + m * 16 + r;
          #pragma unroll
          for (int n = 0; n < 4; ++n)
            qlora[row * 1536 + (wcol + n * 16 + l15)] = f2bf(acc[m][n][r]);
        }
    } else if (wcol < 2048) {  // compressed_kv -> out cols 6208 + (col-1536)
      #pragma unroll
      for (int m = 0; m < 4; ++m)
        #pragma unroll
        for (int r = 0; r < 4; ++r) {
          const long row = r0 + m * 16 + r;
          #pragma unroll
          for (int n = 0; n < 4; ++n)
            out[row * 6720 + (wcol + n * 16 + l15 + 4672)] = acc[m][n][r];
        }
    } else if (wcol == 2048) {  // k_pe + RoPE -> out cols 6144..6207
      #pragma unroll
      for (int m = 0; m < 4; ++m)
        #pragma unroll
        for (int r = 0; r < 4; ++r) {
          const long row = r0 + m * 16 + r;
          #pragma unroll
          for (int n = 0; n < 4; ++n) {
            const int d = n * 16 + l15;
            const float cv = cosp[row * 64 + d];
            const float sv = sinp[row * 64 + d];
            const float v = acc[m][n][r];
            const float rot = (n < 2) ? -acc[m][n + 2][r] : acc[m][n - 2][r];
            out[row * 6720 + 6144 + d] = v * cv + rot * sv;
          }
        }
    }
    // wcol >= 2112: padded garbage, dropped
  } else {
    if ((wcol % 192) != 128) {  // q_nope block: plain copy
      #pragma unroll
      for (int m = 0; m < 4; ++m)
        #pragma unroll
        for (int r = 0; r < 4; ++r) {
          const long row = r0 + m * 16 + r;
          #pragma unroll
          for (int n = 0; n < 4; ++n)
            out[row * 6720 + (wcol + n * 16 + l15)] = acc[m][n][r];
        }
    } else {  // q_pe 64-block: RoPE (d pairs with d+-32 => frags n and n^stride2, same lane)
      #pragma unroll
      for (int m = 0; m < 4; ++m)
        #pragma unroll
        for (int r = 0; r < 4; ++r) {
          const long row = r0 + m * 16 + r;
          #pragma unroll
          for (int n = 0; n < 4; ++n) {
            const int d = n * 16 + l15;
            const float cv = cosp[row * 64 + d];
            const float sv = sinp[row * 64 + d];
            const float v = acc[m][n][r];
            const float rot = (n < 2) ? -acc[m][n + 2][r] : acc[m][n - 2][r];
            out[row * 6720 + wcol + d] = v * cv + rot * sv;
          }
        }
    }
  }
}

// ---------------- launch ----------------

extern "C" void kernel_launch(void* const* d_in, const int* in_sizes, int n_in,
                              void* d_out, int out_size, void* d_ws, size_t ws_size,
                              hipStream_t stream) {
  const float* x    = (const float*)d_in[0];
  const float* cosp = (const float*)d_in[1];
  const float* sinp = (const float*)d_in[2];
  const float* Wqa  = (const float*)d_in[3];
  const float* Wqb  = (const float*)d_in[4];
  const float* Wkva = (const float*)d_in[5];
  float* out = (float*)d_out;

  char* ws = (char*)d_ws;
  // ws layout (bytes):
  //   x_bf16   : 8192*4096*2      = 67108864
  //   W1 (Wqa rows 0..1535 | Wkva rows 1536..2111 | zero 2112..2175) : 2176*4096*2 = 17825792
  //   Wqb_bf16 : 6144*1536*2      = 18874368
  //   q_lora   : 8192*1536*2      = 25165824   (total 128974848)
  __hip_bfloat16* xb  = (__hip_bfloat16*)ws;
  __hip_bfloat16* w1  = (__hip_bfloat16*)(ws + 67108864L);
  __hip_bfloat16* wqb = (__hip_bfloat16*)(ws + 67108864L + 17825792L);
  unsigned short* ql  = (unsigned short*)(ws + 67108864L + 17825792L + 18874368L);

  cvt_bf16_kernel<<<2048, 256, 0, stream>>>(x,   (unsigned short*)xb,  8192L * 4096 / 4);
  cvt_bf16_kernel<<<1024, 256, 0, stream>>>(Wqa, (unsigned short*)w1,  1536L * 4096 / 4);
  cvt_pad_kernel<<<640, 256, 0, stream>>>(Wkva, (unsigned short*)(w1 + 1536L * 4096),
                                          576L * 4096 / 4, 640L * 4096 / 4);
  cvt_bf16_kernel<<<1024, 256, 0, stream>>>(Wqb, (unsigned short*)wqb, 6144L * 1536 / 4);

  dim3 gA(64, 17);  // M/128 x 2176/128
  mla_gemm<0><<<gA, 256, 0, stream>>>(xb, w1, ql, cosp, sinp, out, 4096);
  dim3 gB(64, 48);  // M/128 x 6144/128
  mla_gemm<1><<<gB, 256, 0, stream>>>((const __hip_bfloat16*)ql, wqb, nullptr, cosp, sinp, out, 1536);
}

// Round 2
// 407.236 us; speedup vs baseline: 1.3953x; 1.3953x over previous
//
#include <hip/hip_runtime.h>
#include <hip/hip_bf16.h>
#include <stdint.h>

typedef __bf16 bf16x8 __attribute__((ext_vector_type(8)));
typedef float f32x4 __attribute__((ext_vector_type(4)));

#define AS3 __attribute__((address_space(3)))
#define AS1 __attribute__((address_space(1)))
#define LDS_BUF 49152  // A 32KB + B 16KB per K-step

static __device__ __forceinline__ unsigned short f2bf(float f) {
  unsigned int u = __float_as_uint(f);
  u += 0x7FFF + ((u >> 16) & 1);   // round-to-nearest-even
  return (unsigned short)(u >> 16);
}

// ---------------- fp32 -> bf16 conversion kernels ----------------

extern "C" __global__ void cvt_bf16_kernel(const float* __restrict__ src,
                                           unsigned short* __restrict__ dst,
                                           long n4) {
  long i = (long)blockIdx.x * blockDim.x + threadIdx.x;
  const long stride = (long)gridDim.x * blockDim.x;
  for (; i < n4; i += stride) {
    const float4 v = ((const float4*)src)[i];
    ushort4 o;
    o.x = f2bf(v.x); o.y = f2bf(v.y); o.z = f2bf(v.z); o.w = f2bf(v.w);
    ((ushort4*)dst)[i] = o;
  }
}

extern "C" __global__ void cvt_pad_kernel(const float* __restrict__ src,
                                          unsigned short* __restrict__ dst,
                                          long nsrc4, long ntot4) {
  long i = (long)blockIdx.x * blockDim.x + threadIdx.x;
  const long stride = (long)gridDim.x * blockDim.x;
  for (; i < ntot4; i += stride) {
    ushort4 o = {0, 0, 0, 0};
    if (i < nsrc4) {
      const float4 v = ((const float4*)src)[i];
      o.x = f2bf(v.x); o.y = f2bf(v.y); o.z = f2bf(v.z); o.w = f2bf(v.w);
    }
    ((ushort4*)dst)[i] = o;
  }
}

// ---------------- bf16 NT GEMM (C = A * Bw^T), 256x128 tile, BK=64 ----------------
// 8 waves, wave tile 64x64 (wr=wave>>1 in [0,4), wc=wave&1).
// 3-buffer LDS pipeline: compute buf[t%3], stage step t+2 into buf[(t+2)%3].
// Counted vmcnt(6): 6 global_load_lds per wave per step; never drains to 0 mid-loop.
// Swizzle: LDS dest linear (global_load_lds), global source k16-slot XOR row&7,
// ds_read applies same XOR -> 2-way max bank aliasing (free).

template <int EPI>
__global__ __launch_bounds__(512, 2)
void mla_gemm(const __hip_bfloat16* __restrict__ A,
              const __hip_bfloat16* __restrict__ Bw,
              unsigned short* __restrict__ qlora,
              const float* __restrict__ cosp,
              const float* __restrict__ sinp,
              float* __restrict__ out,
              const int K, const int nBn) {
  extern __shared__ __align__(128) char lds[];
  const int tid = threadIdx.x;
  const int lane = tid & 63;
  const int wave = tid >> 6;
  const int wr = wave >> 1, wc = wave & 1;
  const int l15 = lane & 15, lhi = lane >> 4;

  // XCD-aware block swizzle (gridDim.x divisible by 8)
  const int nwg = gridDim.x;
  const int cpx = nwg >> 3;
  const int swzid = ((int)blockIdx.x & 7) * cpx + ((int)blockIdx.x >> 3);
  const int bm = swzid / nBn;
  const int bn = swzid - bm * nBn;
  const long brow = (long)bm * 256;
  const int bcol = bn * 128;

  // ---- staging geometry ----
  // one global_load_lds per wave covers 8 rows x 128B; lane l -> row +(l>>3), slot l&7.
  const int srow = tid >> 3;                         // 0..63
  const int swz8 = ((tid & 7) ^ (srow & 7)) * 8;     // source k16-slot XOR row&7 (elements)
  const long s64K = 64L * (long)K;                   // 64 rows stride
  const __hip_bfloat16* aP = A + (brow + srow) * (long)K + swz8;
  const __hip_bfloat16* bP = Bw + ((long)bcol + srow) * (long)K + swz8;
  const int waveB = wave << 10;                      // wave*1024 (implicit lane*16 added by HW)

  // ---- fragment-read geometry ----
  const int aRowB = (wr * 64 + l15) * 128;           // + mf*2048 + kphys*16
  const int bRowB = 32768 + (wc * 64 + l15) * 128;   // + nf*2048 + kphys*16
  const int kph0 = (lhi ^ (l15 & 7)) * 16;           // kk=0 physical slot byte
  // kk=1: kph0 ^ 64

  f32x4 acc[4][4] = {};
  const int T = K >> 6;

  auto stageA = [&](int t2, int nxOff, int j) {
    __builtin_amdgcn_global_load_lds(
        (AS1 void*)(aP + (long)t2 * 64 + (long)j * s64K),
        (AS3 void*)(lds + nxOff + j * 8192 + waveB), 16, 0, 0);
  };
  auto stageB = [&](int t2, int nxOff, int j) {
    __builtin_amdgcn_global_load_lds(
        (AS1 void*)(bP + (long)t2 * 64 + (long)j * s64K),
        (AS3 void*)(lds + nxOff + 32768 + j * 8192 + waveB), 16, 0, 0);
  };

  // prologue: stage steps 0 (buf0) and 1 (buf1) -> 12 loads outstanding
  #pragma unroll
  for (int j = 0; j < 4; ++j) stageA(0, 0, j);
  #pragma unroll
  for (int j = 0; j < 2; ++j) stageB(0, 0, j);
  #pragma unroll
  for (int j = 0; j < 4; ++j) stageA(1, LDS_BUF, j);
  #pragma unroll
  for (int j = 0; j < 2; ++j) stageB(1, LDS_BUF, j);

  int cur = 0;
  for (int t = 0; t < T; ++t) {
    // oldest-drain: <=6 outstanding leaves only step t+1's loads in flight
    if (t < T - 1) asm volatile("s_waitcnt vmcnt(6)" ::: "memory");
    else           asm volatile("s_waitcnt vmcnt(0)" ::: "memory");
    __builtin_amdgcn_s_barrier();   // all waves' step-t staging landed; step t-1 reads done

    const int curOff = cur * LDS_BUF;
    int nx = cur + 2; if (nx >= 3) nx -= 3;
    const int nxOff = nx * LDS_BUF;
    const bool doSt = (t + 2) < T;

    // ---- phase 1: kk = 0 ----
    {
      bf16x8 af[4], bv[4];
      #pragma unroll
      for (int mf = 0; mf < 4; ++mf)
        af[mf] = *(const bf16x8*)(lds + curOff + aRowB + mf * 2048 + kph0);
      #pragma unroll
      for (int nf = 0; nf < 4; ++nf)
        bv[nf] = *(const bf16x8*)(lds + curOff + bRowB + nf * 2048 + kph0);
      if (doSt) { stageA(t + 2, nxOff, 0); stageA(t + 2, nxOff, 1); stageA(t + 2, nxOff, 2); }
      __builtin_amdgcn_s_setprio(1);
      #pragma unroll
      for (int mf = 0; mf < 4; ++mf)
        #pragma unroll
        for (int nf = 0; nf < 4; ++nf)
          acc[mf][nf] = __builtin_amdgcn_mfma_f32_16x16x32_bf16(af[mf], bv[nf], acc[mf][nf], 0, 0, 0);
      __builtin_amdgcn_s_setprio(0);
    }
    __builtin_amdgcn_s_barrier();
    // ---- phase 2: kk = 1 ----
    {
      const int kph1 = kph0 ^ 64;
      bf16x8 af[4], bv[4];
      #pragma unroll
      for (int mf = 0; mf < 4; ++mf)
        af[mf] = *(const bf16x8*)(lds + curOff + aRowB + mf * 2048 + kph1);
      #pragma unroll
      for (int nf = 0; nf < 4; ++nf)
        bv[nf] = *(const bf16x8*)(lds + curOff + bRowB + nf * 2048 + kph1);
      if (doSt) { stageA(t + 2, nxOff, 3); stageB(t + 2, nxOff, 0); stageB(t + 2, nxOff, 1); }
      __builtin_amdgcn_s_setprio(1);
      #pragma unroll
      for (int mf = 0; mf < 4; ++mf)
        #pragma unroll
        for (int nf = 0; nf < 4; ++nf)
          acc[mf][nf] = __builtin_amdgcn_mfma_f32_16x16x32_bf16(af[mf], bv[nf], acc[mf][nf], 0, 0, 0);
      __builtin_amdgcn_s_setprio(0);
    }
    cur = cur + 1; if (cur == 3) cur = 0;
  }

  // ---- epilogue ----
  // C/D frag: col = l15 (frag nf), row = lhi*4 + reg (frag mf)
  const int wcol = bcol + wc * 64;
  const long r0 = brow + wr * 64 + lhi * 4;

  if constexpr (EPI == 0) {
    if (wcol < 1536) {  // q_lora (bf16, row stride 1536)
      #pragma unroll
      for (int mf = 0; mf < 4; ++mf)
        #pragma unroll
        for (int r = 0; r < 4; ++r) {
          const long row = r0 + mf * 16 + r;
          #pragma unroll
          for (int nf = 0; nf < 4; ++nf)
            qlora[row * 1536 + (wcol + nf * 16 + l15)] = f2bf(acc[mf][nf][r]);
        }
    } else if (wcol < 2048) {  // compressed_kv -> out cols 6208 + (col-1536)
      #pragma unroll
      for (int mf = 0; mf < 4; ++mf)
        #pragma unroll
        for (int r = 0; r < 4; ++r) {
          const long row = r0 + mf * 16 + r;
          #pragma unroll
          for (int nf = 0; nf < 4; ++nf)
            out[row * 6720 + (wcol + nf * 16 + l15 + 4672)] = acc[mf][nf][r];
        }
    } else if (wcol == 2048) {  // k_pe + RoPE -> out cols 6144..6207
      #pragma unroll
      for (int mf = 0; mf < 4; ++mf)
        #pragma unroll
        for (int r = 0; r < 4; ++r) {
          const long row = r0 + mf * 16 + r;
          #pragma unroll
          for (int nf = 0; nf < 4; ++nf) {
            const int d = nf * 16 + l15;
            const float cv = cosp[row * 64 + d];
            const float sv = sinp[row * 64 + d];
            const float v = acc[mf][nf][r];
            const float rot = (nf < 2) ? -acc[mf][nf + 2][r] : acc[mf][nf - 2][r];
            out[row * 6720 + 6144 + d] = v * cv + rot * sv;
          }
        }
    }
    // wcol >= 2112: padded garbage, dropped
  } else {
    if ((wcol % 192) != 128) {  // q_nope block: plain copy
      #pragma unroll
      for (int mf = 0; mf < 4; ++mf)
        #pragma unroll
        for (int r = 0; r < 4; ++r) {
          const long row = r0 + mf * 16 + r;
          #pragma unroll
          for (int nf = 0; nf < 4; ++nf)
            out[row * 6720 + (wcol + nf * 16 + l15)] = acc[mf][nf][r];
        }
    } else {  // q_pe 64-block: RoPE (d pairs with d+-32 => frags nf and nf+-2, same lane)
      #pragma unroll
      for (int mf = 0; mf < 4; ++mf)
        #pragma unroll
        for (int r = 0; r < 4; ++r) {
          const long row = r0 + mf * 16 + r;
          #pragma unroll
          for (int nf = 0; nf < 4; ++nf) {
            const int d = nf * 16 + l15;
            const float cv = cosp[row * 64 + d];
            const float sv = sinp[row * 64 + d];
            const float v = acc[mf][nf][r];
            const float rot = (nf < 2) ? -acc[mf][nf + 2][r] : acc[mf][nf - 2][r];
            out[row * 6720 + wcol + d] = v * cv + rot * sv;
          }
        }
    }
  }
}

// ---------------- launch ----------------

extern "C" void kernel_launch(void* const* d_in, const int* in_sizes, int n_in,
                              void* d_out, int out_size, void* d_ws, size_t ws_size,
                              hipStream_t stream) {
  const float* x    = (const float*)d_in[0];
  const float* cosp = (const float*)d_in[1];
  const float* sinp = (const float*)d_in[2];
  const float* Wqa  = (const float*)d_in[3];
  const float* Wqb  = (const float*)d_in[4];
  const float* Wkva = (const float*)d_in[5];
  float* out = (float*)d_out;

  char* ws = (char*)d_ws;
  // ws layout: x_bf16 (64MB) | W1 = Wqa rows 0..1535 + Wkva rows 1536..2111 + pad..2175
  //            | Wqb_bf16 | q_lora bf16
  __hip_bfloat16* xb  = (__hip_bfloat16*)ws;
  __hip_bfloat16* w1  = (__hip_bfloat16*)(ws + 67108864L);
  __hip_bfloat16* wqb = (__hip_bfloat16*)(ws + 67108864L + 17825792L);
  unsigned short* ql  = (unsigned short*)(ws + 67108864L + 17825792L + 18874368L);

  cvt_bf16_kernel<<<2048, 256, 0, stream>>>(x,   (unsigned short*)xb,  8192L * 4096 / 4);
  cvt_bf16_kernel<<<1024, 256, 0, stream>>>(Wqa, (unsigned short*)w1,  1536L * 4096 / 4);
  cvt_pad_kernel<<<640, 256, 0, stream>>>(Wkva, (unsigned short*)(w1 + 1536L * 4096),
                                          576L * 4096 / 4, 640L * 4096 / 4);
  cvt_bf16_kernel<<<1024, 256, 0, stream>>>(Wqb, (unsigned short*)wqb, 6144L * 1536 / 4);

  (void)hipFuncSetAttribute((const void*)&mla_gemm<0>,
                            hipFuncAttributeMaxDynamicSharedMemorySize, 3 * LDS_BUF);
  (void)hipFuncSetAttribute((const void*)&mla_gemm<1>,
                            hipFuncAttributeMaxDynamicSharedMemorySize, 3 * LDS_BUF);

  // GEMM-A: M=8192 N=2176 K=4096 -> 32 x 17 = 544 blocks (div by 8)
  mla_gemm<0><<<dim3(544), 512, 3 * LDS_BUF, stream>>>(xb, w1, ql, cosp, sinp, out, 4096, 17);
  // GEMM-B: M=8192 N=6144 K=1536 -> 32 x 48 = 1536 blocks (div by 8)
  mla_gemm<1><<<dim3(1536), 512, 3 * LDS_BUF, stream>>>((const __hip_bfloat16*)ql, wqb,
                                                        nullptr, cosp, sinp, out, 1536, 48);
}